// Round 4
// baseline (518.246 us; speedup 1.0000x reference)
//
#include <hip/hip_runtime.h>

typedef float  f32x4 __attribute__((ext_vector_type(4)));
typedef short  s16x8 __attribute__((ext_vector_type(8)));
typedef unsigned short u16;

// ---- workspace layout (bytes) ----
#define OFF_E     0ULL            // e  bf16 LDS-image tiles [512][32KiB]   16 MiB
#define OFF_ET    16777216ULL     // eT bf16 image tiles [8][128][16KiB]    16 MiB
#define OFF_EPART 33554432ULL     // Epart f32 [16][8][512][128]            32 MiB
#define OFF_GT    67108864ULL     // Gt bf16 image tiles [8][8][16KiB]       1 MiB
#define OFF_WT    68157440ULL     // Wt bf16 image tiles [8][16KiB]        128 KiB
#define OFF_ZP    68288512ULL     // zpart f32 [512][128]                  256 KiB
#define OFF_BAR   68550656ULL     // grid-barrier counters u32[8]            4 KiB
#define WS_NEED   68554752ULL

#define NBLK 512u

// async global->LDS, 16B per lane, wave-uniform LDS base + lane*16
#define GLL16(g, l)                                                          \
  __builtin_amdgcn_global_load_lds(                                          \
      (const __attribute__((address_space(1))) void*)(g),                    \
      (__attribute__((address_space(3))) void*)(l), 16, 0, 0)

// 3-bit octet-permutation key for 64-element (8-octet) rows
#define KEY3(r) ((((r) >> 3) ^ ((r) << 1)) & 7)

__device__ __forceinline__ u16 f2bf(float f) {
  unsigned u = __float_as_uint(f);
  return (u16)((u + 0x8000u) >> 16);          // round-half-up to bf16
}
__device__ __forceinline__ unsigned pack2(float a, float b) {
  unsigned ua = __float_as_uint(a), ub = __float_as_uint(b);
  return ((ua + 0x8000u) >> 16) | ((ub + 0x8000u) & 0xffff0000u);
}

// device-scope grid barrier: release fence -> arrive -> spin (device-scope
// RMW read, cannot see stale per-XCD L2) -> acquire fence.
__device__ __forceinline__ void gbar(unsigned* cnt) {
  __syncthreads();
  if (threadIdx.x == 0) {
    __threadfence();                                   // release my block's writes
    atomicAdd(cnt, 1u);
    while (atomicAdd(cnt, 0u) < NBLK) __builtin_amdgcn_s_sleep(2);
    __threadfence();                                   // acquire others' writes
  }
  __syncthreads();
}

// ------------------------------------------------------------------
__global__ void k_init(unsigned* bar) {
  if (threadIdx.x < 8) bar[threadIdx.x] = 0u;
}

// ------------------------------------------------------------------
// One persistent kernel, 512 blocks x 256 threads (2 blocks/CU exact fit),
// 5 phases separated by grid barriers.  Each phase is a verbatim port of
// the verified R3 kernels (bit-identical per-element math).
__global__ __launch_bounds__(256, 2) void k_fused(
    const float* __restrict__ x, const float* __restrict__ W,
    float* __restrict__ out, u16* __restrict__ eImg, u16* __restrict__ eTImg,
    float* __restrict__ Epart, u16* __restrict__ GtImg, u16* __restrict__ WtImg,
    float* __restrict__ zpart, unsigned* bar) {
  __shared__ __align__(16) char SMEM[67584];           // 66 KiB
  const int tid = threadIdx.x;
  const int bid = blockIdx.x;
  const int lane = tid & 63, wave = tid >> 6;
  const int l15 = lane & 15, quad = lane >> 4;

  // ================= phase 0: Wt image =================
  if (tid < 128) {
    int idx = bid * 128 + tid;                 // 65536 total
    int h = idx & 127, c = idx >> 7;
    int kt = c >> 6, oct = (c >> 3) & 7, t = c & 7;
    WtImg[kt * 8192 + h * 64 + ((oct ^ (h & 7)) * 8) + t] = f2bf(W[c * 128 + h]);
  }
  gbar(bar + 0);

  // ================= phase 1: logits -> e, eT, zpart =================
  {
    u16* smem = (u16*)SMEM;                    // lA0 lA1 lB0 lB1, 16 KiB each
    float* zs = (float*)(SMEM + 65536);
    u16* const sm = smem;
    const int mt = bid;                        // 0..511
    const int rowBase = mt << 7;
    const int q = tid & 3, rb = tid >> 2;

    f32x4 acc[2][8];
#pragma unroll
    for (int i = 0; i < 2; ++i)
#pragma unroll
      for (int j = 0; j < 8; ++j) acc[i][j] = (f32x4){0.f, 0.f, 0.f, 0.f};

    f32x4 xv[2][4];

    {
      const char* srcB = (const char*)WtImg + wave * 4096 + lane * 16;
      char* dstB = (char*)(smem + 16384) + wave * 4096;
#pragma unroll
      for (int i = 0; i < 4; ++i) GLL16(srcB + i * 1024, dstB + i * 1024);
    }
#pragma unroll
    for (int rep = 0; rep < 2; ++rep) {
      const int r = rb + rep * 64;
      const float* src = x + (size_t)(rowBase + r) * 512 + q * 4;
#pragma unroll
      for (int j = 0; j < 4; ++j) xv[rep][j] = *(const f32x4*)(src + j * 16);
    }
#pragma unroll
    for (int rep = 0; rep < 2; ++rep) {
      const int r = rb + rep * 64;
#pragma unroll
      for (int j = 0; j < 4; ++j) {
        const int chunk = (2 * j + (q >> 1)) ^ (r & 7);
        unsigned* dst = (unsigned*)&smem[r * 64 + chunk * 8 + (q & 1) * 4];
        dst[0] = pack2(xv[rep][j][0], xv[rep][j][1]);
        dst[1] = pack2(xv[rep][j][2], xv[rep][j][3]);
      }
    }
    __syncthreads();

    for (int kt = 0; kt < 8; ++kt) {
      const int cur = kt & 1;
      u16* lAc = smem + (cur ? 8192 : 0);
      u16* lBc = smem + 16384 + (cur ? 8192 : 0);
      if (kt < 7) {
        const char* srcB = (const char*)WtImg + (size_t)(kt + 1) * 16384 + wave * 4096 + lane * 16;
        char* dstB = (char*)(smem + 16384 + (cur ? 0 : 8192)) + wave * 4096;
#pragma unroll
        for (int i = 0; i < 4; ++i) GLL16(srcB + i * 1024, dstB + i * 1024);
        const int k0 = (kt + 1) << 6;
#pragma unroll
        for (int rep = 0; rep < 2; ++rep) {
          const int r = rb + rep * 64;
          const float* src = x + (size_t)(rowBase + r) * 512 + k0 + q * 4;
#pragma unroll
          for (int j = 0; j < 4; ++j) xv[rep][j] = *(const f32x4*)(src + j * 16);
        }
      }
#pragma unroll
      for (int kk = 0; kk < 2; ++kk) {
        s16x8 af[2], bf[8];
#pragma unroll
        for (int i = 0; i < 2; ++i) {
          const int r = wave * 32 + i * 16 + l15;
          af[i] = *(const s16x8*)&lAc[r * 64 + (((kk * 4 + quad) ^ (r & 7)) * 8)];
        }
#pragma unroll
        for (int j = 0; j < 8; ++j) {
          const int r = j * 16 + l15;
          bf[j] = *(const s16x8*)&lBc[r * 64 + (((kk * 4 + quad) ^ (r & 7)) * 8)];
        }
#pragma unroll
        for (int i = 0; i < 2; ++i)
#pragma unroll
          for (int j = 0; j < 8; ++j)
            acc[i][j] = __builtin_amdgcn_mfma_f32_16x16x32_bf16(af[i], bf[j], acc[i][j], 0, 0, 0);
      }
      if (kt < 7) {
        u16* lAn = smem + (cur ? 0 : 8192);
#pragma unroll
        for (int rep = 0; rep < 2; ++rep) {
          const int r = rb + rep * 64;
#pragma unroll
          for (int j = 0; j < 4; ++j) {
            const int chunk = (2 * j + (q >> 1)) ^ (r & 7);
            unsigned* dst = (unsigned*)&lAn[r * 64 + chunk * 8 + (q & 1) * 4];
            dst[0] = pack2(xv[rep][j][0], xv[rep][j][1]);
            dst[1] = pack2(xv[rep][j][2], xv[rep][j][3]);
          }
        }
      }
      __syncthreads();
    }

    float ex[2][8][4];
    float cs[8];
#pragma unroll
    for (int j = 0; j < 8; ++j) cs[j] = 0.f;
#pragma unroll
    for (int i = 0; i < 2; ++i)
#pragma unroll
      for (int j = 0; j < 8; ++j)
#pragma unroll
        for (int rr = 0; rr < 4; ++rr) {
          float l = acc[i][j][rr];
          l = fminf(fmaxf(l, -30.f), 30.f);
          float t = __expf(l);
          ex[i][j][rr] = t;
          cs[j] += t;
        }
#pragma unroll
    for (int j = 0; j < 8; ++j) {
      cs[j] += __shfl_xor(cs[j], 16);
      cs[j] += __shfl_xor(cs[j], 32);
    }
    if (quad == 0) {
#pragma unroll
      for (int j = 0; j < 8; ++j) zs[wave * 128 + j * 16 + l15] = cs[j];
    }
    __syncthreads();

#pragma unroll
    for (int i = 0; i < 2; ++i)
#pragma unroll
      for (int j = 0; j < 8; ++j)
#pragma unroll
        for (int rr = 0; rr < 4; ++rr) {
          int s = wave * 32 + i * 16 + quad * 4 + rr;
          int h = j * 16 + l15;
          sm[s * 128 + (((h >> 3) ^ (s & 15)) * 8) + (h & 7)] = f2bf(ex[i][j][rr]);
        }
    if (tid < 128)
      zpart[mt * 128 + tid] = zs[tid] + zs[128 + tid] + zs[256 + tid] + zs[384 + tid];
    __syncthreads();

    {
      char* dstT = (char*)eImg + (size_t)mt * 32768;
      const char* smB = (const char*)sm;
#pragma unroll
      for (int pass = 0; pass < 8; ++pass) {
        s16x8 v = *(const s16x8*)(smB + pass * 4096 + tid * 16);
        *(s16x8*)(dstT + pass * 4096 + tid * 16) = v;
      }
    }
    {
      int ck = tid & 15, hb = tid >> 4;
      int cH = ck >> 3, oct = ck & 7;
      u16* dstT = eTImg + (size_t)mt * 16384 + cH * 8192;
#pragma unroll
      for (int pass = 0; pass < 8; ++pass) {
        int h = hb + pass * 16;
        s16x8 v;
#pragma unroll
        for (int j = 0; j < 8; ++j) {
          int s = ck * 8 + j;
          v[j] = (short)sm[s * 128 + (((h >> 3) ^ (s & 15)) * 8) + (h & 7)];
        }
        *(s16x8*)(dstT + h * 64 + ((oct ^ KEY3(h)) * 8)) = v;
      }
    }
  }
  gbar(bar + 1);

  // ================= phase 2: Epart =================
  {
    u16* smem = (u16*)SMEM;                    // lA0 lA1 lB0 lB1, 16 KiB each
    const int nt = bid & 3;
    const int b = (bid >> 2) & 7;
    const int kc = bid >> 5;                   // 0..15
    const int cw = tid & 15, rg = tid >> 4;

    f32x4 acc[2][8];
#pragma unroll
    for (int i = 0; i < 2; ++i)
#pragma unroll
      for (int j = 0; j < 8; ++j) acc[i][j] = (f32x4){0.f, 0.f, 0.f, 0.f};

    f32x4 xv[4][2];

    {
      const char* srcB = (const char*)eTImg + ((size_t)(b * 128 + kc * 8) * 16384) +
                         wave * 4096 + lane * 16;
      char* dstB = (char*)(smem + 16384) + wave * 4096;
#pragma unroll
      for (int i = 0; i < 4; ++i) GLL16(srcB + i * 1024, dstB + i * 1024);
    }
    {
      const float* src = x + ((size_t)(b * 8192 + kc * 512 + rg * 4) * 512 + nt * 128 + cw * 8);
#pragma unroll
      for (int j = 0; j < 4; ++j) {
        xv[j][0] = *(const f32x4*)(src + (size_t)j * 512);
        xv[j][1] = *(const f32x4*)(src + (size_t)j * 512 + 4);
      }
    }
#pragma unroll
    for (int i = 0; i < 8; ++i) {
      const int cl = cw * 8 + i;
      unsigned wv[2];
      if (i < 4) {
        wv[0] = pack2(xv[0][0][i], xv[1][0][i]);
        wv[1] = pack2(xv[2][0][i], xv[3][0][i]);
      } else {
        wv[0] = pack2(xv[0][1][i - 4], xv[1][1][i - 4]);
        wv[1] = pack2(xv[2][1][i - 4], xv[3][1][i - 4]);
      }
      *(unsigned*)&smem[cl * 64 + (((rg >> 1) ^ KEY3(cl)) * 8) + (rg & 1) * 4] = wv[0];
      *(unsigned*)&smem[cl * 64 + (((rg >> 1) ^ KEY3(cl)) * 8) + (rg & 1) * 4 + 2] = wv[1];
    }
    __syncthreads();

    for (int kt = 0; kt < 8; ++kt) {
      const int cur = kt & 1;
      u16* lAc = smem + (cur ? 8192 : 0);
      u16* lBc = smem + 16384 + (cur ? 8192 : 0);
      if (kt < 7) {
        const char* srcB = (const char*)eTImg +
                           ((size_t)(b * 128 + kc * 8 + kt + 1) * 16384) +
                           wave * 4096 + lane * 16;
        char* dstB = (char*)(smem + 16384 + (cur ? 0 : 8192)) + wave * 4096;
#pragma unroll
        for (int i = 0; i < 4; ++i) GLL16(srcB + i * 1024, dstB + i * 1024);
        const float* src = x + ((size_t)(b * 8192 + kc * 512 + (kt + 1) * 64 + rg * 4) * 512 +
                                nt * 128 + cw * 8);
#pragma unroll
        for (int j = 0; j < 4; ++j) {
          xv[j][0] = *(const f32x4*)(src + (size_t)j * 512);
          xv[j][1] = *(const f32x4*)(src + (size_t)j * 512 + 4);
        }
      }
#pragma unroll
      for (int kk = 0; kk < 2; ++kk) {
        s16x8 af[2], bf[8];
#pragma unroll
        for (int i = 0; i < 2; ++i) {
          const int r = wave * 32 + i * 16 + l15;
          af[i] = *(const s16x8*)&lAc[r * 64 + (((kk * 4 + quad) ^ KEY3(r)) * 8)];
        }
#pragma unroll
        for (int j = 0; j < 8; ++j) {
          const int n = j * 16 + l15;
          bf[j] = *(const s16x8*)&lBc[n * 64 + (((kk * 4 + quad) ^ KEY3(n)) * 8)];
        }
#pragma unroll
        for (int i = 0; i < 2; ++i)
#pragma unroll
          for (int j = 0; j < 8; ++j)
            acc[i][j] = __builtin_amdgcn_mfma_f32_16x16x32_bf16(af[i], bf[j], acc[i][j], 0, 0, 0);
      }
      if (kt < 7) {
        u16* lAn = smem + (cur ? 0 : 8192);
#pragma unroll
        for (int i = 0; i < 8; ++i) {
          const int cl = cw * 8 + i;
          unsigned wv[2];
          if (i < 4) {
            wv[0] = pack2(xv[0][0][i], xv[1][0][i]);
            wv[1] = pack2(xv[2][0][i], xv[3][0][i]);
          } else {
            wv[0] = pack2(xv[0][1][i - 4], xv[1][1][i - 4]);
            wv[1] = pack2(xv[2][1][i - 4], xv[3][1][i - 4]);
          }
          *(unsigned*)&lAn[cl * 64 + (((rg >> 1) ^ KEY3(cl)) * 8) + (rg & 1) * 4] = wv[0];
          *(unsigned*)&lAn[cl * 64 + (((rg >> 1) ^ KEY3(cl)) * 8) + (rg & 1) * 4 + 2] = wv[1];
        }
      }
      __syncthreads();
    }
    float* dst = Epart + ((size_t)(kc * 8 + b) * 512 + nt * 128) * 128;
#pragma unroll
    for (int i = 0; i < 2; ++i)
#pragma unroll
      for (int j = 0; j < 8; ++j)
#pragma unroll
        for (int rr = 0; rr < 4; ++rr) {
          int c = wave * 32 + i * 16 + quad * 4 + rr;
          int h = j * 16 + l15;
          dst[(size_t)c * 128 + h] = acc[i][j][rr];
        }
  }
  gbar(bar + 2);

  // ================= phase 3: Gt (+fused zmerge), blocks 0..255 =================
  if (bid < 256) {
    float* rzs = (float*)SMEM;
    const int b = bid >> 5;
    if (tid < 128) {
      float z = 0.f;
#pragma unroll 8
      for (int i = 0; i < 64; ++i) z += zpart[(b * 64 + i) * 128 + tid];
      rzs[tid] = 1.0f / (z * z);
    }
    __syncthreads();
    int idx = bid * 256 + tid;
    int h8 = idx & 15, c = (idx >> 4) & 511;
    f32x4 s0 = {0.f, 0.f, 0.f, 0.f}, s1 = {0.f, 0.f, 0.f, 0.f};
#pragma unroll
    for (int p = 0; p < 16; ++p) {
      const float* src = Epart + (((size_t)(p * 8 + b) * 512 + c) * 128 + h8 * 8);
      s0 += *(const f32x4*)src;
      s1 += *(const f32x4*)(src + 4);
    }
    f32x4 z0 = *(const f32x4*)&rzs[h8 * 8];
    f32x4 z1 = *(const f32x4*)&rzs[h8 * 8 + 4];
    unsigned ov[4];
    ov[0] = pack2(s0[0] * z0[0], s0[1] * z0[1]);
    ov[1] = pack2(s0[2] * z0[2], s0[3] * z0[3]);
    ov[2] = pack2(s1[0] * z1[0], s1[1] * z1[1]);
    ov[3] = pack2(s1[2] * z1[2], s1[3] * z1[3]);
    int r = c & 63, ct = c >> 6;
    *(s16x8*)(GtImg + ((size_t)(b * 8 + ct) * 8192) + r * 128 + ((h8 ^ (r & 15)) * 8)) =
        *(s16x8*)ov;
  }
  gbar(bar + 3);

  // ================= phase 4: out =================
  {
    u16* lA = (u16*)SMEM;                     // 32 KiB (e tile)
    u16* lBd = (u16*)(SMEM + 32768);          // 2 x 16 KiB (Gt tiles)
    const int st = bid & 63;
    const int b = bid >> 6;

    {
      const char* src = (const char*)eImg + ((size_t)(b * 64 + st) * 32768) +
                        wave * 8192 + lane * 16;
      char* dst = (char*)lA + wave * 8192;
#pragma unroll
      for (int i = 0; i < 8; ++i) GLL16(src + i * 1024, dst + i * 1024);
    }
    {
      const char* src = (const char*)GtImg + ((size_t)(b * 8) * 16384) +
                        wave * 4096 + lane * 16;
      char* dst = (char*)lBd + wave * 4096;
#pragma unroll
      for (int i = 0; i < 4; ++i) GLL16(src + i * 1024, dst + i * 1024);
    }
    __syncthreads();

    for (int ct = 0; ct < 8; ++ct) {
      const int cur = ct & 1;
      u16* lBc = lBd + (cur ? 8192 : 0);
      if (ct < 7) {
        const char* src = (const char*)GtImg + ((size_t)(b * 8 + ct + 1) * 16384) +
                          wave * 4096 + lane * 16;
        char* dst = (char*)(lBd + (cur ? 0 : 8192)) + wave * 4096;
#pragma unroll
        for (int i = 0; i < 4; ++i) GLL16(src + i * 1024, dst + i * 1024);
      }
      f32x4 acc[2][4];
#pragma unroll
      for (int i = 0; i < 2; ++i)
#pragma unroll
        for (int j = 0; j < 4; ++j) acc[i][j] = (f32x4){0.f, 0.f, 0.f, 0.f};
#pragma unroll
      for (int kk = 0; kk < 4; ++kk) {
        s16x8 af[2], bf[4];
#pragma unroll
        for (int i = 0; i < 2; ++i) {
          const int r = wave * 32 + i * 16 + l15;
          af[i] = *(const s16x8*)&lA[r * 128 + (((kk * 4 + quad) ^ (r & 15)) * 8)];
        }
#pragma unroll
        for (int j = 0; j < 4; ++j) {
          const int n = j * 16 + l15;
          bf[j] = *(const s16x8*)&lBc[n * 128 + (((kk * 4 + quad) ^ (n & 15)) * 8)];
        }
#pragma unroll
        for (int i = 0; i < 2; ++i)
#pragma unroll
          for (int j = 0; j < 4; ++j)
            acc[i][j] = __builtin_amdgcn_mfma_f32_16x16x32_bf16(af[i], bf[j], acc[i][j], 0, 0, 0);
      }
#pragma unroll
      for (int i = 0; i < 2; ++i)
#pragma unroll
        for (int j = 0; j < 4; ++j)
#pragma unroll
          for (int rr = 0; rr < 4; ++rr) {
            int s = wave * 32 + i * 16 + quad * 4 + rr;
            int c = ct * 64 + j * 16 + l15;
            __builtin_nontemporal_store(
                acc[i][j][rr], &out[(size_t)(b * 8192 + st * 128 + s) * 512 + c]);
          }
      __syncthreads();
    }
  }
}

// ------------------------------------------------------------------
extern "C" void kernel_launch(void* const* d_in, const int* in_sizes, int n_in,
                              void* d_out, int out_size, void* d_ws, size_t ws_size,
                              hipStream_t stream) {
  if (ws_size < (size_t)WS_NEED) return;  // need ~65.4 MiB scratch
  const float* x = (const float*)d_in[0];
  const float* W = (const float*)d_in[1];
  float* out = (float*)d_out;
  char* ws = (char*)d_ws;
  u16* eImg = (u16*)(ws + OFF_E);
  u16* eTImg = (u16*)(ws + OFF_ET);
  float* Epart = (float*)(ws + OFF_EPART);
  u16* GtImg = (u16*)(ws + OFF_GT);
  u16* WtImg = (u16*)(ws + OFF_WT);
  float* zpart = (float*)(ws + OFF_ZP);
  unsigned* bar = (unsigned*)(ws + OFF_BAR);

  k_init<<<1, 64, 0, stream>>>(bar);
  k_fused<<<NBLK, 256, 0, stream>>>(x, W, out, eImg, eTImg, Epart, GtImg, WtImg,
                                    zpart, bar);
}

// Round 5
// 301.858 us; speedup vs baseline: 1.7169x; 1.7169x over previous
//
#include <hip/hip_runtime.h>

typedef float  f32x4 __attribute__((ext_vector_type(4)));
typedef short  s16x8 __attribute__((ext_vector_type(8)));
typedef unsigned u32x2 __attribute__((ext_vector_type(2)));
typedef unsigned short u16;

// ---- workspace layout (bytes) ----
#define OFF_E     0ULL            // e  bf16 LDS-image tiles [512][32KiB]   16 MiB
#define OFF_ET    16777216ULL     // eT bf16 image tiles [8][128][16KiB]    16 MiB
#define OFF_EPART 33554432ULL     // Epart f32 [16][8][512][128]            32 MiB
#define OFF_GT    67108864ULL     // Gt bf16 image tiles [8][8][16KiB]       1 MiB
#define OFF_WT    68157440ULL     // Wt bf16 image tiles [8][16KiB]        128 KiB
#define OFF_ZP    68288512ULL     // zpart f32 [512][128]                  256 KiB
#define OFF_RZ2   68550656ULL     // (unused)                                4 KiB
#define WS_NEED   68554752ULL

// async global->LDS, 16B per lane, wave-uniform LDS base + lane*16
#define GLL16(g, l)                                                          \
  __builtin_amdgcn_global_load_lds(                                          \
      (const __attribute__((address_space(1))) void*)(g),                    \
      (__attribute__((address_space(3))) void*)(l), 16, 0, 0)

// 3-bit octet-permutation key for 64-element (8-octet) rows
#define KEY3(r) ((((r) >> 3) ^ ((r) << 1)) & 7)

__device__ __forceinline__ u16 f2bf(float f) {
  unsigned u = __float_as_uint(f);
  return (u16)((u + 0x8000u) >> 16);          // round-half-up to bf16
}
__device__ __forceinline__ unsigned pack2(float a, float b) {
  unsigned ua = __float_as_uint(a), ub = __float_as_uint(b);
  return ((ua + 0x8000u) >> 16) | ((ub + 0x8000u) & 0xffff0000u);
}

// ------------------------------------------------------------------
// k_wt: Wt stored as k_logits_e's lB LDS image:
//   img[kt][h*64 + ((oct ^ (h&7))*8) + t] = W[kt*64 + oct*8 + t][h]
__global__ __launch_bounds__(256) void k_wt(const float* __restrict__ W,
                                            u16* __restrict__ WtImg) {
  int idx = blockIdx.x * 256 + threadIdx.x;    // 65536 total
  int h = idx & 127, c = idx >> 7;
  int kt = c >> 6, oct = (c >> 3) & 7, t = c & 7;
  WtImg[kt * 8192 + h * 64 + ((oct ^ (h & 7)) * 8) + t] = f2bf(W[c * 128 + h]);
}

// ------------------------------------------------------------------
// k_logits_e: 2-phase pipelined (verified R3).  Per kt (64-c K-step):
// prefetch Wt(kt+1) via gll + x(kt+1) into regs, MFMA on current buffers,
// pack x into the other lA buffer, ONE barrier.  Epilogue: e-image (raw
// dump) + eT-image (two 16KiB 64-s tiles, KEY3 layout) + zpart.
__global__ __launch_bounds__(256) void k_logits_e(
    const float* __restrict__ x, const u16* __restrict__ WtImg,
    u16* __restrict__ eImg, u16* __restrict__ eTImg, float* __restrict__ zpart) {
  __shared__ __align__(16) u16 smem[4 * 8192];   // lA0 lA1 lB0 lB1, 16 KiB each
  __shared__ float zs[512];
  u16* const sm = smem;                          // epilogue reuse (32 KiB)
  const int tid = threadIdx.x;
  const int lane = tid & 63, wave = tid >> 6;
  const int l15 = lane & 15, quad = lane >> 4;
  const int mt = blockIdx.x;                   // 0..511  (== b*64 + sc)
  const int rowBase = mt << 7;
  const int q = tid & 3, rb = tid >> 2;

  f32x4 acc[2][8];
#pragma unroll
  for (int i = 0; i < 2; ++i)
#pragma unroll
    for (int j = 0; j < 8; ++j) acc[i][j] = (f32x4){0.f, 0.f, 0.f, 0.f};

  f32x4 xv[2][4];

  // ---- prologue: fill buffers 0
  {
    const char* srcB = (const char*)WtImg + wave * 4096 + lane * 16;
    char* dstB = (char*)(smem + 16384) + wave * 4096;
#pragma unroll
    for (int i = 0; i < 4; ++i) GLL16(srcB + i * 1024, dstB + i * 1024);
  }
#pragma unroll
  for (int rep = 0; rep < 2; ++rep) {
    const int r = rb + rep * 64;
    const float* src = x + (size_t)(rowBase + r) * 512 + q * 4;
#pragma unroll
    for (int j = 0; j < 4; ++j) xv[rep][j] = *(const f32x4*)(src + j * 16);
  }
#pragma unroll
  for (int rep = 0; rep < 2; ++rep) {
    const int r = rb + rep * 64;
#pragma unroll
    for (int j = 0; j < 4; ++j) {
      const int chunk = (2 * j + (q >> 1)) ^ (r & 7);
      unsigned* dst = (unsigned*)&smem[r * 64 + chunk * 8 + (q & 1) * 4];
      dst[0] = pack2(xv[rep][j][0], xv[rep][j][1]);
      dst[1] = pack2(xv[rep][j][2], xv[rep][j][3]);
    }
  }
  __syncthreads();

  for (int kt = 0; kt < 8; ++kt) {
    const int cur = kt & 1;
    u16* lAc = smem + (cur ? 8192 : 0);
    u16* lBc = smem + 16384 + (cur ? 8192 : 0);
    if (kt < 7) {
      const char* srcB = (const char*)WtImg + (size_t)(kt + 1) * 16384 + wave * 4096 + lane * 16;
      char* dstB = (char*)(smem + 16384 + (cur ? 0 : 8192)) + wave * 4096;
#pragma unroll
      for (int i = 0; i < 4; ++i) GLL16(srcB + i * 1024, dstB + i * 1024);
      const int k0 = (kt + 1) << 6;
#pragma unroll
      for (int rep = 0; rep < 2; ++rep) {
        const int r = rb + rep * 64;
        const float* src = x + (size_t)(rowBase + r) * 512 + k0 + q * 4;
#pragma unroll
        for (int j = 0; j < 4; ++j) xv[rep][j] = *(const f32x4*)(src + j * 16);
      }
    }
    // ---- MFMA on current buffers (prefetch loads in flight)
#pragma unroll
    for (int kk = 0; kk < 2; ++kk) {
      s16x8 af[2], bf[8];
#pragma unroll
      for (int i = 0; i < 2; ++i) {
        const int r = wave * 32 + i * 16 + l15;
        af[i] = *(const s16x8*)&lAc[r * 64 + (((kk * 4 + quad) ^ (r & 7)) * 8)];
      }
#pragma unroll
      for (int j = 0; j < 8; ++j) {
        const int r = j * 16 + l15;
        bf[j] = *(const s16x8*)&lBc[r * 64 + (((kk * 4 + quad) ^ (r & 7)) * 8)];
      }
#pragma unroll
      for (int i = 0; i < 2; ++i)
#pragma unroll
        for (int j = 0; j < 8; ++j)
          acc[i][j] = __builtin_amdgcn_mfma_f32_16x16x32_bf16(af[i], bf[j], acc[i][j], 0, 0, 0);
    }
    // ---- pack prefetched x into the other lA buffer
    if (kt < 7) {
      u16* lAn = smem + (cur ? 0 : 8192);
#pragma unroll
      for (int rep = 0; rep < 2; ++rep) {
        const int r = rb + rep * 64;
#pragma unroll
        for (int j = 0; j < 4; ++j) {
          const int chunk = (2 * j + (q >> 1)) ^ (r & 7);
          unsigned* dst = (unsigned*)&lAn[r * 64 + chunk * 8 + (q & 1) * 4];
          dst[0] = pack2(xv[rep][j][0], xv[rep][j][1]);
          dst[1] = pack2(xv[rep][j][2], xv[rep][j][3]);
        }
      }
    }
    __syncthreads();
  }

  float ex[2][8][4];
  float cs[8];
#pragma unroll
  for (int j = 0; j < 8; ++j) cs[j] = 0.f;
#pragma unroll
  for (int i = 0; i < 2; ++i)
#pragma unroll
    for (int j = 0; j < 8; ++j)
#pragma unroll
      for (int rr = 0; rr < 4; ++rr) {
        float l = acc[i][j][rr];
        l = fminf(fmaxf(l, -30.f), 30.f);
        float t = __expf(l);
        ex[i][j][rr] = t;
        cs[j] += t;
      }
#pragma unroll
  for (int j = 0; j < 8; ++j) {
    cs[j] += __shfl_xor(cs[j], 16);
    cs[j] += __shfl_xor(cs[j], 32);
  }
  if (quad == 0) {
#pragma unroll
    for (int j = 0; j < 8; ++j) zs[wave * 128 + j * 16 + l15] = cs[j];
  }
  __syncthreads();

#pragma unroll
  for (int i = 0; i < 2; ++i)
#pragma unroll
    for (int j = 0; j < 8; ++j)
#pragma unroll
      for (int rr = 0; rr < 4; ++rr) {
        int s = wave * 32 + i * 16 + quad * 4 + rr;
        int h = j * 16 + l15;
        sm[s * 128 + (((h >> 3) ^ (s & 15)) * 8) + (h & 7)] = f2bf(ex[i][j][rr]);
      }
  if (tid < 128)
    zpart[mt * 128 + tid] = zs[tid] + zs[128 + tid] + zs[256 + tid] + zs[384 + tid];
  __syncthreads();

  // ---- e image: raw linear dump of sm (sm layout == k_out lA image)
  {
    char* dstT = (char*)eImg + (size_t)mt * 32768;
    const char* smB = (const char*)sm;
#pragma unroll
    for (int pass = 0; pass < 8; ++pass) {
      s16x8 v = *(const s16x8*)(smB + pass * 4096 + tid * 16);
      *(s16x8*)(dstT + pass * 4096 + tid * 16) = v;
    }
  }
  // ---- eT image: gather transpose into two 16KiB 64-s tiles (KEY3 layout)
  {
    int ck = tid & 15, hb = tid >> 4;
    int cH = ck >> 3, oct = ck & 7;
    u16* dstT = eTImg + (size_t)mt * 16384 + cH * 8192;
#pragma unroll
    for (int pass = 0; pass < 8; ++pass) {
      int h = hb + pass * 16;
      s16x8 v;
#pragma unroll
      for (int j = 0; j < 8; ++j) {
        int s = ck * 8 + j;
        v[j] = (short)sm[s * 128 + (((h >> 3) ^ (s & 15)) * 8) + (h & 7)];
      }
      *(s16x8*)(dstT + h * 64 + ((oct ^ KEY3(h)) * 8)) = v;
    }
  }
}

// ------------------------------------------------------------------
// k_E: E^T[c][h] = sum_s x[s][c]*eT[h][s].  2-phase pipelined (verified R3)
// + XCD-chunked block swizzle: the 4 nt-blocks sharing an eT slice land on
// the same XCD so eT is fetched into one L2, not four.
__global__ __launch_bounds__(256) void k_E(const float* __restrict__ x,
                                           const u16* __restrict__ eTImg,
                                           float* __restrict__ Epart) {
  __shared__ __align__(16) u16 smem[4 * 8192];   // lA0 lA1 lB0 lB1, 16 KiB each
  const int tid = threadIdx.x;
  const int lane = tid & 63, wave = tid >> 6;
  const int l15 = lane & 15, quad = lane >> 4;
  // XCD-chunked bijection (512 = 8 XCD x 64): chunk of 64 consecutive
  // work-items per XCD; within a chunk nt varies fastest.
  const int wg = blockIdx.x;
  const int sw = (wg & 7) * 64 + (wg >> 3);
  const int nt = sw & 3;        // c band 0..3 (128 wide)
  const int b = (sw >> 2) & 7;
  const int kc = sw >> 5;       // 0..15: 512-s chunk
  const int cw = tid & 15, rg = tid >> 4;   // A-stage: c-octet / 4-s group

  f32x4 acc[2][8];
#pragma unroll
  for (int i = 0; i < 2; ++i)
#pragma unroll
    for (int j = 0; j < 8; ++j) acc[i][j] = (f32x4){0.f, 0.f, 0.f, 0.f};

  f32x4 xv[4][2];

  // ---- prologue: fill buffers 0 (s-chunk kt=0)
  {
    const char* srcB = (const char*)eTImg + ((size_t)(b * 128 + kc * 8) * 16384) +
                       wave * 4096 + lane * 16;
    char* dstB = (char*)(smem + 16384) + wave * 4096;
#pragma unroll
    for (int i = 0; i < 4; ++i) GLL16(srcB + i * 1024, dstB + i * 1024);
  }
  {
    const float* src = x + ((size_t)(b * 8192 + kc * 512 + rg * 4) * 512 + nt * 128 + cw * 8);
#pragma unroll
    for (int j = 0; j < 4; ++j) {
      xv[j][0] = *(const f32x4*)(src + (size_t)j * 512);
      xv[j][1] = *(const f32x4*)(src + (size_t)j * 512 + 4);
    }
  }
#pragma unroll
  for (int i = 0; i < 8; ++i) {
    const int cl = cw * 8 + i;
    unsigned wv[2];
    if (i < 4) {
      wv[0] = pack2(xv[0][0][i], xv[1][0][i]);
      wv[1] = pack2(xv[2][0][i], xv[3][0][i]);
    } else {
      wv[0] = pack2(xv[0][1][i - 4], xv[1][1][i - 4]);
      wv[1] = pack2(xv[2][1][i - 4], xv[3][1][i - 4]);
    }
    *(unsigned*)&smem[cl * 64 + (((rg >> 1) ^ KEY3(cl)) * 8) + (rg & 1) * 4] = wv[0];
    *(unsigned*)&smem[cl * 64 + (((rg >> 1) ^ KEY3(cl)) * 8) + (rg & 1) * 4 + 2] = wv[1];
  }
  __syncthreads();

  for (int kt = 0; kt < 8; ++kt) {          // 8 steps of 64 s
    const int cur = kt & 1;
    u16* lAc = smem + (cur ? 8192 : 0);
    u16* lBc = smem + 16384 + (cur ? 8192 : 0);
    if (kt < 7) {
      const char* srcB = (const char*)eTImg +
                         ((size_t)(b * 128 + kc * 8 + kt + 1) * 16384) +
                         wave * 4096 + lane * 16;
      char* dstB = (char*)(smem + 16384 + (cur ? 0 : 8192)) + wave * 4096;
#pragma unroll
      for (int i = 0; i < 4; ++i) GLL16(srcB + i * 1024, dstB + i * 1024);
      const float* src = x + ((size_t)(b * 8192 + kc * 512 + (kt + 1) * 64 + rg * 4) * 512 +
                              nt * 128 + cw * 8);
#pragma unroll
      for (int j = 0; j < 4; ++j) {
        xv[j][0] = *(const f32x4*)(src + (size_t)j * 512);
        xv[j][1] = *(const f32x4*)(src + (size_t)j * 512 + 4);
      }
    }
    // ---- MFMA on current buffers
#pragma unroll
    for (int kk = 0; kk < 2; ++kk) {
      s16x8 af[2], bf[8];
#pragma unroll
      for (int i = 0; i < 2; ++i) {
        const int r = wave * 32 + i * 16 + l15;
        af[i] = *(const s16x8*)&lAc[r * 64 + (((kk * 4 + quad) ^ KEY3(r)) * 8)];
      }
#pragma unroll
      for (int j = 0; j < 8; ++j) {
        const int n = j * 16 + l15;
        bf[j] = *(const s16x8*)&lBc[n * 64 + (((kk * 4 + quad) ^ KEY3(n)) * 8)];
      }
#pragma unroll
      for (int i = 0; i < 2; ++i)
#pragma unroll
        for (int j = 0; j < 8; ++j)
          acc[i][j] = __builtin_amdgcn_mfma_f32_16x16x32_bf16(af[i], bf[j], acc[i][j], 0, 0, 0);
    }
    // ---- pack prefetched x into other lA buffer
    if (kt < 7) {
      u16* lAn = smem + (cur ? 0 : 8192);
#pragma unroll
      for (int i = 0; i < 8; ++i) {
        const int cl = cw * 8 + i;
        unsigned wv[2];
        if (i < 4) {
          wv[0] = pack2(xv[0][0][i], xv[1][0][i]);
          wv[1] = pack2(xv[2][0][i], xv[3][0][i]);
        } else {
          wv[0] = pack2(xv[0][1][i - 4], xv[1][1][i - 4]);
          wv[1] = pack2(xv[2][1][i - 4], xv[3][1][i - 4]);
        }
        *(unsigned*)&lAn[cl * 64 + (((rg >> 1) ^ KEY3(cl)) * 8) + (rg & 1) * 4] = wv[0];
        *(unsigned*)&lAn[cl * 64 + (((rg >> 1) ^ KEY3(cl)) * 8) + (rg & 1) * 4 + 2] = wv[1];
      }
    }
    __syncthreads();
  }
  float* dst = Epart + ((size_t)(kc * 8 + b) * 512 + nt * 128) * 128;
#pragma unroll
  for (int i = 0; i < 2; ++i)
#pragma unroll
    for (int j = 0; j < 8; ++j)
#pragma unroll
      for (int rr = 0; rr < 4; ++rr) {
        int c = wave * 32 + i * 16 + quad * 4 + rr;
        int h = j * 16 + l15;
        dst[(size_t)c * 128 + h] = acc[i][j][rr];
      }
}

// ------------------------------------------------------------------
// k_G (+fused zmerge): now 512 blocks (4 h per thread, f32x4) for 2x the
// latency-hiding parallelism of the strided partial-sum reads.  Per-element
// arithmetic order identical to the verified version (bit-identical).
__global__ __launch_bounds__(256) void k_G(const float* __restrict__ Epart,
                                           const float* __restrict__ zpart,
                                           u16* __restrict__ GtImg) {
  __shared__ float rzs[128];
  const int tid = threadIdx.x;
  const int bidx = blockIdx.x;        // 0..511, b uniform per block
  const int b = bidx >> 6;
  if (tid < 128) {
    float z = 0.f;
#pragma unroll 8
    for (int i = 0; i < 64; ++i) z += zpart[(b * 64 + i) * 128 + tid];
    rzs[tid] = 1.0f / (z * z);
  }
  __syncthreads();
  int idx = bidx * 256 + tid;          // 131072 threads, 4 h each
  int h4 = idx & 31, c = (idx >> 5) & 511;
  f32x4 s = {0.f, 0.f, 0.f, 0.f};
#pragma unroll
  for (int p = 0; p < 16; ++p)
    s += *(const f32x4*)(Epart + (((size_t)(p * 8 + b) * 512 + c) * 128 + h4 * 4));
  f32x4 z = *(const f32x4*)&rzs[h4 * 4];
  u32x2 ov;
  ov.x = pack2(s[0] * z[0], s[1] * z[1]);
  ov.y = pack2(s[2] * z[2], s[3] * z[3]);
  int r = c & 63, ct = c >> 6, h8 = h4 >> 1;
  *(u32x2*)(GtImg + ((size_t)(b * 8 + ct) * 8192) + r * 128 +
            ((h8 ^ (r & 15)) * 8) + (h4 & 1) * 4) = ov;
}

// ------------------------------------------------------------------
// k_out: out[s][c] = e[s][:] @ G[:, c].  2-phase pipelined (verified R3)
// + XCD-chunked swizzle: each XCD owns one batch b -> Gt[b] cached once
// per L2 and the out region per XCD is one contiguous 16 MiB span.
__global__ __launch_bounds__(256) void k_out(const u16* __restrict__ eImg,
                                             const u16* __restrict__ GtImg,
                                             float* __restrict__ out) {
  __shared__ __align__(16) u16 lA[128 * 128];      // 32 KiB (e tile)
  __shared__ __align__(16) u16 lBd[2 * 64 * 128];  // 2 x 16 KiB (Gt tiles)
  const int tid = threadIdx.x;
  const int lane = tid & 63, wave = tid >> 6;
  const int l15 = lane & 15, quad = lane >> 4;
  const int wg = blockIdx.x;                       // 512 = 8 XCD x 64
  const int sw = (wg & 7) * 64 + (wg >> 3);
  const int st = sw & 63;
  const int b = sw >> 6;

  // ---- prologue: stage A (e image, once) + B(ct=0)
  {
    const char* src = (const char*)eImg + ((size_t)(b * 64 + st) * 32768) +
                      wave * 8192 + lane * 16;
    char* dst = (char*)lA + wave * 8192;
#pragma unroll
    for (int i = 0; i < 8; ++i) GLL16(src + i * 1024, dst + i * 1024);
  }
  {
    const char* src = (const char*)GtImg + ((size_t)(b * 8) * 16384) +
                      wave * 4096 + lane * 16;
    char* dst = (char*)lBd + wave * 4096;
#pragma unroll
    for (int i = 0; i < 4; ++i) GLL16(src + i * 1024, dst + i * 1024);
  }
  __syncthreads();

  for (int ct = 0; ct < 8; ++ct) {
    const int cur = ct & 1;
    u16* lBc = lBd + (cur ? 8192 : 0);
    if (ct < 7) {
      const char* src = (const char*)GtImg + ((size_t)(b * 8 + ct + 1) * 16384) +
                        wave * 4096 + lane * 16;
      char* dst = (char*)(lBd + (cur ? 0 : 8192)) + wave * 4096;
#pragma unroll
      for (int i = 0; i < 4; ++i) GLL16(src + i * 1024, dst + i * 1024);
    }
    f32x4 acc[2][4];
#pragma unroll
    for (int i = 0; i < 2; ++i)
#pragma unroll
      for (int j = 0; j < 4; ++j) acc[i][j] = (f32x4){0.f, 0.f, 0.f, 0.f};
#pragma unroll
    for (int kk = 0; kk < 4; ++kk) {
      s16x8 af[2], bf[4];
#pragma unroll
      for (int i = 0; i < 2; ++i) {
        const int r = wave * 32 + i * 16 + l15;
        af[i] = *(const s16x8*)&lA[r * 128 + (((kk * 4 + quad) ^ (r & 15)) * 8)];
      }
#pragma unroll
      for (int j = 0; j < 4; ++j) {
        const int n = j * 16 + l15;
        bf[j] = *(const s16x8*)&lBc[n * 128 + (((kk * 4 + quad) ^ (n & 15)) * 8)];
      }
#pragma unroll
      for (int i = 0; i < 2; ++i)
#pragma unroll
        for (int j = 0; j < 4; ++j)
          acc[i][j] = __builtin_amdgcn_mfma_f32_16x16x32_bf16(af[i], bf[j], acc[i][j], 0, 0, 0);
    }
#pragma unroll
    for (int i = 0; i < 2; ++i)
#pragma unroll
      for (int j = 0; j < 4; ++j)
#pragma unroll
        for (int rr = 0; rr < 4; ++rr) {
          int s = wave * 32 + i * 16 + quad * 4 + rr;
          int c = ct * 64 + j * 16 + l15;
          __builtin_nontemporal_store(
              acc[i][j][rr], &out[(size_t)(b * 8192 + st * 128 + s) * 512 + c]);
        }
    __syncthreads();
  }
}

// ------------------------------------------------------------------
extern "C" void kernel_launch(void* const* d_in, const int* in_sizes, int n_in,
                              void* d_out, int out_size, void* d_ws, size_t ws_size,
                              hipStream_t stream) {
  if (ws_size < (size_t)WS_NEED) return;  // need ~65.4 MiB scratch
  const float* x = (const float*)d_in[0];
  const float* W = (const float*)d_in[1];
  float* out = (float*)d_out;
  char* ws = (char*)d_ws;
  u16* eImg = (u16*)(ws + OFF_E);
  u16* eTImg = (u16*)(ws + OFF_ET);
  float* Epart = (float*)(ws + OFF_EPART);
  u16* GtImg = (u16*)(ws + OFF_GT);
  u16* WtImg = (u16*)(ws + OFF_WT);
  float* zpart = (float*)(ws + OFF_ZP);

  k_wt<<<256, 256, 0, stream>>>(W, WtImg);
  k_logits_e<<<512, 256, 0, stream>>>(x, WtImg, eImg, eTImg, zpart);
  k_E<<<512, 256, 0, stream>>>(x, eTImg, Epart);
  k_G<<<512, 256, 0, stream>>>(Epart, zpart, GtImg);
  k_out<<<512, 256, 0, stream>>>(eImg, GtImg, out);
}

// Round 6
// 297.894 us; speedup vs baseline: 1.7397x; 1.0133x over previous
//
#include <hip/hip_runtime.h>

typedef float  f32x4 __attribute__((ext_vector_type(4)));
typedef short  s16x8 __attribute__((ext_vector_type(8)));
typedef unsigned u32x2 __attribute__((ext_vector_type(2)));
typedef unsigned short u16;

// ---- workspace layout (bytes) ----
#define OFF_E     0ULL            // e  bf16 LDS-image tiles [512][32KiB]   16 MiB
#define OFF_ET    16777216ULL     // eT bf16 image tiles [8][128][16KiB]    16 MiB
#define OFF_EPART 33554432ULL     // Epart f32 [16][8][512][128]            32 MiB
#define OFF_GT    67108864ULL     // Gt bf16 image tiles [8][8][16KiB]       1 MiB
#define OFF_WT    68157440ULL     // Wt bf16 image tiles [8][16KiB]        128 KiB
#define OFF_ZP    68288512ULL     // zpart f32 [512][128]                  256 KiB
#define OFF_RZ2   68550656ULL     // (unused)                                4 KiB
#define WS_NEED   68554752ULL

// async global->LDS, 16B per lane, wave-uniform LDS base + lane*16
#define GLL16(g, l)                                                          \
  __builtin_amdgcn_global_load_lds(                                          \
      (const __attribute__((address_space(1))) void*)(g),                    \
      (__attribute__((address_space(3))) void*)(l), 16, 0, 0)

// 3-bit octet-permutation key for 64-element (8-octet) rows
#define KEY3(r) ((((r) >> 3) ^ ((r) << 1)) & 7)

__device__ __forceinline__ u16 f2bf(float f) {
  unsigned u = __float_as_uint(f);
  return (u16)((u + 0x8000u) >> 16);          // round-half-up to bf16
}
__device__ __forceinline__ unsigned pack2(float a, float b) {
  unsigned ua = __float_as_uint(a), ub = __float_as_uint(b);
  return ((ua + 0x8000u) >> 16) | ((ub + 0x8000u) & 0xffff0000u);
}

// ------------------------------------------------------------------
// k_wt: Wt stored as k_logits_e's lB LDS image:
//   img[kt][h*64 + ((oct ^ (h&7))*8) + t] = W[kt*64 + oct*8 + t][h]
__global__ __launch_bounds__(256) void k_wt(const float* __restrict__ W,
                                            u16* __restrict__ WtImg) {
  int idx = blockIdx.x * 256 + threadIdx.x;    // 65536 total
  int h = idx & 127, c = idx >> 7;
  int kt = c >> 6, oct = (c >> 3) & 7, t = c & 7;
  WtImg[kt * 8192 + h * 64 + ((oct ^ (h & 7)) * 8) + t] = f2bf(W[c * 128 + h]);
}

// ------------------------------------------------------------------
// x-load / x-pack helpers for k_logits_e (per-thread 8 f32x4 = one K-step)
#define LOADX(xv, kt_)                                                       \
  {                                                                          \
    const int k0_ = (kt_) << 6;                                              \
    _Pragma("unroll") for (int rep = 0; rep < 2; ++rep) {                    \
      const int r_ = rb + rep * 64;                                          \
      const float* src_ = x + (size_t)(rowBase + r_) * 512 + k0_ + q * 4;    \
      _Pragma("unroll") for (int j = 0; j < 4; ++j)                          \
          xv[rep][j] = *(const f32x4*)(src_ + j * 16);                       \
    }                                                                        \
  }
#define PACKX(xv, dstbuf)                                                    \
  {                                                                          \
    _Pragma("unroll") for (int rep = 0; rep < 2; ++rep) {                    \
      const int r_ = rb + rep * 64;                                          \
      _Pragma("unroll") for (int j = 0; j < 4; ++j) {                        \
        const int chunk_ = (2 * j + (q >> 1)) ^ (r_ & 7);                    \
        unsigned* dst_ = (unsigned*)&dstbuf[r_ * 64 + chunk_ * 8 + (q & 1) * 4]; \
        dst_[0] = pack2(xv[rep][j][0], xv[rep][j][1]);                       \
        dst_[1] = pack2(xv[rep][j][2], xv[rep][j][3]);                       \
      }                                                                      \
    }                                                                        \
  }

// k_logits_e: 2-phase pipelined, x prefetch now TWO K-steps deep
// (ping-pong xvA/xvB; load of x(kt+2) issued at top of step kt, consumed
// by the pack at step kt+1 -> ~1.5-2 steps of latency coverage).
// Per-element math identical to verified R3/R5 (bit-identical).
__global__ __launch_bounds__(256) void k_logits_e(
    const float* __restrict__ x, const u16* __restrict__ WtImg,
    u16* __restrict__ eImg, u16* __restrict__ eTImg, float* __restrict__ zpart) {
  __shared__ __align__(16) u16 smem[4 * 8192];   // lA0 lA1 lB0 lB1, 16 KiB each
  __shared__ float zs[512];
  u16* const sm = smem;                          // epilogue reuse (32 KiB)
  const int tid = threadIdx.x;
  const int lane = tid & 63, wave = tid >> 6;
  const int l15 = lane & 15, quad = lane >> 4;
  const int mt = blockIdx.x;                   // 0..511  (== b*64 + sc)
  const int rowBase = mt << 7;
  const int q = tid & 3, rb = tid >> 2;

  f32x4 acc[2][8];
#pragma unroll
  for (int i = 0; i < 2; ++i)
#pragma unroll
    for (int j = 0; j < 8; ++j) acc[i][j] = (f32x4){0.f, 0.f, 0.f, 0.f};

  f32x4 xvA[2][4], xvB[2][4];

  // ---- prologue: Wt(0) via gll; x(0)->xvA, x(1)->xvB; pack x(0)
  {
    const char* srcB = (const char*)WtImg + wave * 4096 + lane * 16;
    char* dstB = (char*)(smem + 16384) + wave * 4096;
#pragma unroll
    for (int i = 0; i < 4; ++i) GLL16(srcB + i * 1024, dstB + i * 1024);
  }
  LOADX(xvA, 0)
  LOADX(xvB, 1)
  PACKX(xvA, smem)
  __syncthreads();

#pragma unroll
  for (int kt = 0; kt < 8; ++kt) {
    u16* lAc = smem + ((kt & 1) ? 8192 : 0);
    u16* lBc = smem + 16384 + ((kt & 1) ? 8192 : 0);
    // 1. issue x(kt+2) into the slot just consumed (2-deep pipeline)
    if (kt < 6) {
      if ((kt & 1) == 0) { LOADX(xvA, kt + 2) } else { LOADX(xvB, kt + 2) }
    }
    // 2. prefetch Wt(kt+1) via gll into other B buffer
    if (kt < 7) {
      const char* srcB = (const char*)WtImg + (size_t)(kt + 1) * 16384 + wave * 4096 + lane * 16;
      char* dstB = (char*)(smem + 16384 + ((kt & 1) ? 0 : 8192)) + wave * 4096;
#pragma unroll
      for (int i = 0; i < 4; ++i) GLL16(srcB + i * 1024, dstB + i * 1024);
    }
    // 3. MFMA on current buffers (prefetch loads in flight)
#pragma unroll
    for (int kk = 0; kk < 2; ++kk) {
      s16x8 af[2], bf[8];
#pragma unroll
      for (int i = 0; i < 2; ++i) {
        const int r = wave * 32 + i * 16 + l15;
        af[i] = *(const s16x8*)&lAc[r * 64 + (((kk * 4 + quad) ^ (r & 7)) * 8)];
      }
#pragma unroll
      for (int j = 0; j < 8; ++j) {
        const int r = j * 16 + l15;
        bf[j] = *(const s16x8*)&lBc[r * 64 + (((kk * 4 + quad) ^ (r & 7)) * 8)];
      }
#pragma unroll
      for (int i = 0; i < 2; ++i)
#pragma unroll
        for (int j = 0; j < 8; ++j)
          acc[i][j] = __builtin_amdgcn_mfma_f32_16x16x32_bf16(af[i], bf[j], acc[i][j], 0, 0, 0);
    }
    // 4. pack x(kt+1) (loaded one full step ago) into other lA buffer
    if (kt < 7) {
      u16* lAn = smem + ((kt & 1) ? 0 : 8192);
      if (kt & 1) { PACKX(xvA, lAn) } else { PACKX(xvB, lAn) }
    }
    __syncthreads();
  }

  float ex[2][8][4];
  float cs[8];
#pragma unroll
  for (int j = 0; j < 8; ++j) cs[j] = 0.f;
#pragma unroll
  for (int i = 0; i < 2; ++i)
#pragma unroll
    for (int j = 0; j < 8; ++j)
#pragma unroll
      for (int rr = 0; rr < 4; ++rr) {
        float l = acc[i][j][rr];
        l = fminf(fmaxf(l, -30.f), 30.f);
        float t = __expf(l);
        ex[i][j][rr] = t;
        cs[j] += t;
      }
#pragma unroll
  for (int j = 0; j < 8; ++j) {
    cs[j] += __shfl_xor(cs[j], 16);
    cs[j] += __shfl_xor(cs[j], 32);
  }
  if (quad == 0) {
#pragma unroll
    for (int j = 0; j < 8; ++j) zs[wave * 128 + j * 16 + l15] = cs[j];
  }
  __syncthreads();

#pragma unroll
  for (int i = 0; i < 2; ++i)
#pragma unroll
    for (int j = 0; j < 8; ++j)
#pragma unroll
      for (int rr = 0; rr < 4; ++rr) {
        int s = wave * 32 + i * 16 + quad * 4 + rr;
        int h = j * 16 + l15;
        sm[s * 128 + (((h >> 3) ^ (s & 15)) * 8) + (h & 7)] = f2bf(ex[i][j][rr]);
      }
  if (tid < 128)
    zpart[mt * 128 + tid] = zs[tid] + zs[128 + tid] + zs[256 + tid] + zs[384 + tid];
  __syncthreads();

  // ---- e image: raw linear dump of sm (sm layout == k_out lA image)
  {
    char* dstT = (char*)eImg + (size_t)mt * 32768;
    const char* smB = (const char*)sm;
#pragma unroll
    for (int pass = 0; pass < 8; ++pass) {
      s16x8 v = *(const s16x8*)(smB + pass * 4096 + tid * 16);
      *(s16x8*)(dstT + pass * 4096 + tid * 16) = v;
    }
  }
  // ---- eT image: gather transpose into two 16KiB 64-s tiles (KEY3 layout)
  {
    int ck = tid & 15, hb = tid >> 4;
    int cH = ck >> 3, oct = ck & 7;
    u16* dstT = eTImg + (size_t)mt * 16384 + cH * 8192;
#pragma unroll
    for (int pass = 0; pass < 8; ++pass) {
      int h = hb + pass * 16;
      s16x8 v;
#pragma unroll
      for (int j = 0; j < 8; ++j) {
        int s = ck * 8 + j;
        v[j] = (short)sm[s * 128 + (((h >> 3) ^ (s & 15)) * 8) + (h & 7)];
      }
      *(s16x8*)(dstT + h * 64 + ((oct ^ KEY3(h)) * 8)) = v;
    }
  }
}

// ------------------------------------------------------------------
// x-load / x-pack helpers for k_E (per-thread 8 f32x4 = one 64-s K-step)
#define LOADXE(xv, kt_)                                                      \
  {                                                                          \
    const float* src_ = x + ((size_t)(b * 8192 + kc * 512 + (kt_) * 64 + rg * 4) * 512 + \
                             nt * 128 + cw * 8);                             \
    _Pragma("unroll") for (int j = 0; j < 4; ++j) {                          \
      xv[j][0] = *(const f32x4*)(src_ + (size_t)j * 512);                    \
      xv[j][1] = *(const f32x4*)(src_ + (size_t)j * 512 + 4);                \
    }                                                                        \
  }
#define PACKXE(xv, dstbuf)                                                   \
  {                                                                          \
    _Pragma("unroll") for (int i = 0; i < 8; ++i) {                          \
      const int cl_ = cw * 8 + i;                                            \
      unsigned w0_, w1_;                                                     \
      if (i < 4) {                                                           \
        w0_ = pack2(xv[0][0][i], xv[1][0][i]);                               \
        w1_ = pack2(xv[2][0][i], xv[3][0][i]);                               \
      } else {                                                               \
        w0_ = pack2(xv[0][1][i - 4], xv[1][1][i - 4]);                       \
        w1_ = pack2(xv[2][1][i - 4], xv[3][1][i - 4]);                       \
      }                                                                      \
      *(unsigned*)&dstbuf[cl_ * 64 + (((rg >> 1) ^ KEY3(cl_)) * 8) + (rg & 1) * 4] = w0_; \
      *(unsigned*)&dstbuf[cl_ * 64 + (((rg >> 1) ^ KEY3(cl_)) * 8) + (rg & 1) * 4 + 2] = w1_; \
    }                                                                        \
  }

// k_E: E^T[c][h] = sum_s x[s][c]*eT[h][s].  2-phase pipelined, x prefetch
// TWO K-steps deep (ping-pong xvA/xvB).  XCD-chunked swizzle kept from R5.
__global__ __launch_bounds__(256) void k_E(const float* __restrict__ x,
                                           const u16* __restrict__ eTImg,
                                           float* __restrict__ Epart) {
  __shared__ __align__(16) u16 smem[4 * 8192];   // lA0 lA1 lB0 lB1, 16 KiB each
  const int tid = threadIdx.x;
  const int lane = tid & 63, wave = tid >> 6;
  const int l15 = lane & 15, quad = lane >> 4;
  const int wg = blockIdx.x;
  const int sw = (wg & 7) * 64 + (wg >> 3);      // XCD-chunked bijection
  const int nt = sw & 3;        // c band 0..3 (128 wide)
  const int b = (sw >> 2) & 7;
  const int kc = sw >> 5;       // 0..15: 512-s chunk
  const int cw = tid & 15, rg = tid >> 4;   // A-stage: c-octet / 4-s group

  f32x4 acc[2][8];
#pragma unroll
  for (int i = 0; i < 2; ++i)
#pragma unroll
    for (int j = 0; j < 8; ++j) acc[i][j] = (f32x4){0.f, 0.f, 0.f, 0.f};

  f32x4 xvA[4][2], xvB[4][2];

  // ---- prologue: eT(0) via gll; x(0)->xvA, x(1)->xvB; pack x(0)
  {
    const char* srcB = (const char*)eTImg + ((size_t)(b * 128 + kc * 8) * 16384) +
                       wave * 4096 + lane * 16;
    char* dstB = (char*)(smem + 16384) + wave * 4096;
#pragma unroll
    for (int i = 0; i < 4; ++i) GLL16(srcB + i * 1024, dstB + i * 1024);
  }
  LOADXE(xvA, 0)
  LOADXE(xvB, 1)
  PACKXE(xvA, smem)
  __syncthreads();

#pragma unroll
  for (int kt = 0; kt < 8; ++kt) {          // 8 steps of 64 s
    u16* lAc = smem + ((kt & 1) ? 8192 : 0);
    u16* lBc = smem + 16384 + ((kt & 1) ? 8192 : 0);
    // 1. issue x(kt+2) into the slot just consumed (2-deep pipeline)
    if (kt < 6) {
      if ((kt & 1) == 0) { LOADXE(xvA, kt + 2) } else { LOADXE(xvB, kt + 2) }
    }
    // 2. prefetch eT(kt+1) via gll into other B buffer
    if (kt < 7) {
      const char* srcB = (const char*)eTImg +
                         ((size_t)(b * 128 + kc * 8 + kt + 1) * 16384) +
                         wave * 4096 + lane * 16;
      char* dstB = (char*)(smem + 16384 + ((kt & 1) ? 0 : 8192)) + wave * 4096;
#pragma unroll
      for (int i = 0; i < 4; ++i) GLL16(srcB + i * 1024, dstB + i * 1024);
    }
    // 3. MFMA on current buffers
#pragma unroll
    for (int kk = 0; kk < 2; ++kk) {
      s16x8 af[2], bf[8];
#pragma unroll
      for (int i = 0; i < 2; ++i) {
        const int r = wave * 32 + i * 16 + l15;
        af[i] = *(const s16x8*)&lAc[r * 64 + (((kk * 4 + quad) ^ KEY3(r)) * 8)];
      }
#pragma unroll
      for (int j = 0; j < 8; ++j) {
        const int n = j * 16 + l15;
        bf[j] = *(const s16x8*)&lBc[n * 64 + (((kk * 4 + quad) ^ KEY3(n)) * 8)];
      }
#pragma unroll
      for (int i = 0; i < 2; ++i)
#pragma unroll
        for (int j = 0; j < 8; ++j)
          acc[i][j] = __builtin_amdgcn_mfma_f32_16x16x32_bf16(af[i], bf[j], acc[i][j], 0, 0, 0);
    }
    // 4. pack x(kt+1) (loaded one full step ago) into other lA buffer
    if (kt < 7) {
      u16* lAn = smem + ((kt & 1) ? 0 : 8192);
      if (kt & 1) { PACKXE(xvA, lAn) } else { PACKXE(xvB, lAn) }
    }
    __syncthreads();
  }
  float* dst = Epart + ((size_t)(kc * 8 + b) * 512 + nt * 128) * 128;
#pragma unroll
  for (int i = 0; i < 2; ++i)
#pragma unroll
    for (int j = 0; j < 8; ++j)
#pragma unroll
      for (int rr = 0; rr < 4; ++rr) {
        int c = wave * 32 + i * 16 + quad * 4 + rr;
        int h = j * 16 + l15;
        dst[(size_t)c * 128 + h] = acc[i][j][rr];
      }
}

// ------------------------------------------------------------------
// k_G (+fused zmerge): 512 blocks, 4 h per thread (f32x4).  Per-element
// arithmetic order identical to the verified version (bit-identical).
__global__ __launch_bounds__(256) void k_G(const float* __restrict__ Epart,
                                           const float* __restrict__ zpart,
                                           u16* __restrict__ GtImg) {
  __shared__ float rzs[128];
  const int tid = threadIdx.x;
  const int bidx = blockIdx.x;        // 0..511, b uniform per block
  const int b = bidx >> 6;
  if (tid < 128) {
    float z = 0.f;
#pragma unroll 8
    for (int i = 0; i < 64; ++i) z += zpart[(b * 64 + i) * 128 + tid];
    rzs[tid] = 1.0f / (z * z);
  }
  __syncthreads();
  int idx = bidx * 256 + tid;          // 131072 threads, 4 h each
  int h4 = idx & 31, c = (idx >> 5) & 511;
  f32x4 s = {0.f, 0.f, 0.f, 0.f};
#pragma unroll
  for (int p = 0; p < 16; ++p)
    s += *(const f32x4*)(Epart + (((size_t)(p * 8 + b) * 512 + c) * 128 + h4 * 4));
  f32x4 z = *(const f32x4*)&rzs[h4 * 4];
  u32x2 ov;
  ov.x = pack2(s[0] * z[0], s[1] * z[1]);
  ov.y = pack2(s[2] * z[2], s[3] * z[3]);
  int r = c & 63, ct = c >> 6, h8 = h4 >> 1;
  *(u32x2*)(GtImg + ((size_t)(b * 8 + ct) * 8192) + r * 128 +
            ((h8 ^ (r & 15)) * 8) + (h4 & 1) * 4) = ov;
}

// ------------------------------------------------------------------
// k_out: out[s][c] = e[s][:] @ G[:, c].  2-phase pipelined over 8 ct steps;
// XCD-chunked swizzle (one batch per XCD).  Non-temporal out stores.
__global__ __launch_bounds__(256) void k_out(const u16* __restrict__ eImg,
                                             const u16* __restrict__ GtImg,
                                             float* __restrict__ out) {
  __shared__ __align__(16) u16 lA[128 * 128];      // 32 KiB (e tile)
  __shared__ __align__(16) u16 lBd[2 * 64 * 128];  // 2 x 16 KiB (Gt tiles)
  const int tid = threadIdx.x;
  const int lane = tid & 63, wave = tid >> 6;
  const int l15 = lane & 15, quad = lane >> 4;
  const int wg = blockIdx.x;                       // 512 = 8 XCD x 64
  const int sw = (wg & 7) * 64 + (wg >> 3);
  const int st = sw & 63;
  const int b = sw >> 6;

  // ---- prologue: stage A (e image, once) + B(ct=0)
  {
    const char* src = (const char*)eImg + ((size_t)(b * 64 + st) * 32768) +
                      wave * 8192 + lane * 16;
    char* dst = (char*)lA + wave * 8192;
#pragma unroll
    for (int i = 0; i < 8; ++i) GLL16(src + i * 1024, dst + i * 1024);
  }
  {
    const char* src = (const char*)GtImg + ((size_t)(b * 8) * 16384) +
                      wave * 4096 + lane * 16;
    char* dst = (char*)lBd + wave * 4096;
#pragma unroll
    for (int i = 0; i < 4; ++i) GLL16(src + i * 1024, dst + i * 1024);
  }
  __syncthreads();

  for (int ct = 0; ct < 8; ++ct) {
    const int cur = ct & 1;
    u16* lBc = lBd + (cur ? 8192 : 0);
    if (ct < 7) {
      const char* src = (const char*)GtImg + ((size_t)(b * 8 + ct + 1) * 16384) +
                        wave * 4096 + lane * 16;
      char* dst = (char*)(lBd + (cur ? 0 : 8192)) + wave * 4096;
#pragma unroll
      for (int i = 0; i < 4; ++i) GLL16(src + i * 1024, dst + i * 1024);
    }
    f32x4 acc[2][4];
#pragma unroll
    for (int i = 0; i < 2; ++i)
#pragma unroll
      for (int j = 0; j < 4; ++j) acc[i][j] = (f32x4){0.f, 0.f, 0.f, 0.f};
#pragma unroll
    for (int kk = 0; kk < 4; ++kk) {
      s16x8 af[2], bf[4];
#pragma unroll
      for (int i = 0; i < 2; ++i) {
        const int r = wave * 32 + i * 16 + l15;
        af[i] = *(const s16x8*)&lA[r * 128 + (((kk * 4 + quad) ^ (r & 15)) * 8)];
      }
#pragma unroll
      for (int j = 0; j < 4; ++j) {
        const int n = j * 16 + l15;
        bf[j] = *(const s16x8*)&lBc[n * 128 + (((kk * 4 + quad) ^ (n & 15)) * 8)];
      }
#pragma unroll
      for (int i = 0; i < 2; ++i)
#pragma unroll
        for (int j = 0; j < 4; ++j)
          acc[i][j] = __builtin_amdgcn_mfma_f32_16x16x32_bf16(af[i], bf[j], acc[i][j], 0, 0, 0);
    }
#pragma unroll
    for (int i = 0; i < 2; ++i)
#pragma unroll
      for (int j = 0; j < 4; ++j)
#pragma unroll
        for (int rr = 0; rr < 4; ++rr) {
          int s = wave * 32 + i * 16 + quad * 4 + rr;
          int c = ct * 64 + j * 16 + l15;
          __builtin_nontemporal_store(
              acc[i][j][rr], &out[(size_t)(b * 8192 + st * 128 + s) * 512 + c]);
        }
    __syncthreads();
  }
}

// ------------------------------------------------------------------
extern "C" void kernel_launch(void* const* d_in, const int* in_sizes, int n_in,
                              void* d_out, int out_size, void* d_ws, size_t ws_size,
                              hipStream_t stream) {
  if (ws_size < (size_t)WS_NEED) return;  // need ~65.4 MiB scratch
  const float* x = (const float*)d_in[0];
  const float* W = (const float*)d_in[1];
  float* out = (float*)d_out;
  char* ws = (char*)d_ws;
  u16* eImg = (u16*)(ws + OFF_E);
  u16* eTImg = (u16*)(ws + OFF_ET);
  float* Epart = (float*)(ws + OFF_EPART);
  u16* GtImg = (u16*)(ws + OFF_GT);
  u16* WtImg = (u16*)(ws + OFF_WT);
  float* zpart = (float*)(ws + OFF_ZP);

  k_wt<<<256, 256, 0, stream>>>(W, WtImg);
  k_logits_e<<<512, 256, 0, stream>>>(x, WtImg, eImg, eTImg, zpart);
  k_E<<<512, 256, 0, stream>>>(x, eTImg, Epart);
  k_G<<<512, 256, 0, stream>>>(Epart, zpart, GtImg);
  k_out<<<512, 256, 0, stream>>>(eImg, GtImg, out);
}